// Round 1
// 82.871 us; speedup vs baseline: 1.0764x; 1.0764x over previous
//
#include <hip/hip_runtime.h>
#include <math.h>

#define NPART 4096
#define NBLK  1024
#define NTHR  256
#define IPB   4     // particles (i) per block: one 64-lane wave per i
#define SMAX  256   // local collision-set cap (expected ~60; own i's pre-seeded)
#define PPT   (NPART / NTHR)   // 16 particles staged per thread

// Constants, rounded exactly as the reference's weak-typed doubles -> f32
constexpr float RORC   = (float)(2.5e-5 + 3.15e-6);    // RO + RC
constexpr float RORC2  = RORC * RORC;
constexpr float RRF    = 8e-6f;
constexpr float RR2    = RRF * RRF;
constexpr float TWORC  = (float)(2.0 * 3.15e-6);
constexpr float TWORC2 = TWORC * TWORC;
constexpr float C21RC  = (float)(2.1 * 3.15e-6);
constexpr float RCAND2 = 1.6e-9f;                      // (4e-5)^2 >= 3-hop chain span
constexpr float C_ROT  = (float)(0.2 * 25.0 * 0.0028);
constexpr float C_RN1  = (float)0.07483314773547883;
constexpr float C_SQDT = (float)0.4472135954999579;
constexpr float C_TRV  = (float)(0.2 * 5e-7);
constexpr float C_HALF = (float)0.7071067811865476;
constexpr float C_SQ2T = (float)1.6733200530681511e-07;
constexpr float EPSF   = 1e-14f;

// ---------------------------------------------------------------------------
// Brute-force rewrite vs R13: the per-block 64x64 cell sort (histogram +
// 16-barrier scan + scatter, ~1.1M LDS-conflict cycles, 62 KB LDS) cost more
// than the O(N^2) sweep it avoided at N=4096. Now each block stages all
// positions into LDS once and each own-i's full wave sweeps all 4096
// particles as float4 pairs (32 iters/lane). LDS 62->38.5 KB => 4 blocks/CU,
// 16 waves/CU (was 8). 1024 blocks x IPB=4. S-compaction / Jacobi / epilogue
// arithmetic preserved verbatim from the passing kernel.
// ---------------------------------------------------------------------------
__global__ __launch_bounds__(NTHR, 4) void fused_all(
        const float2* __restrict__ pos, const float2* __restrict__ ori,
        const float* __restrict__ Deltas, const float* __restrict__ rot_noise,
        const float2* __restrict__ trans_noise, float2* __restrict__ out) {
    __shared__ float4   posL4[NPART / 2];     // 32 KB all positions, orig order
    __shared__ float    sred[2 * NTHR];       // 2 KB mean tree
    __shared__ float    res[5][IPB];
    __shared__ unsigned bmap[NPART / 32];     // 512 B
    __shared__ int      Sidx[SMAX];           // 1 KB
    __shared__ float4   posS4[SMAX / 2];      // 2 KB
    __shared__ int      scnt;
    float2* posL = (float2*)posL4;
    float2* posS = (float2*)posS4;

    const int tid  = threadIdx.x;
    const int il   = tid >> 6;            // own-i 0..3 (one wave each)
    const int lane = tid & 63;
    const int gi   = blockIdx.x * IPB + il;

    if (tid == 0) scnt = IPB;             // slots 0..3 = own i's
    if (tid < IPB) Sidx[tid] = blockIdx.x * IPB + tid;
    if (tid < NPART / 32) bmap[tid] = 0u;

    // ---- stage positions -> LDS; accumulate mean partials (same per-thread
    //      k*NTHR+tid mapping and order as the passing kernel) ----
    float mx = 0.f, my = 0.f;
    #pragma unroll
    for (int k = 0; k < PPT; ++k) {
        const float2 v = pos[k * NTHR + tid];
        posL[k * NTHR + tid] = v;
        mx += v.x; my += v.y;
    }
    sred[tid] = mx; sred[NTHR + tid] = my;
    __syncthreads();                      // posL / sred / bmap / Sidx ready

    // ---- A. brute-force sweep: one wave per own-i, float4 = 2 particles ----
    const float2 pi = posL[gi];
    float nr = 0.f, sx = 0.f, sy = 0.f, oxs = 0.f, oys = 0.f;
    #pragma unroll 2
    for (int t = lane; t < NPART / 2; t += 64) {
        const float4 w = posL4[t];
        const float dx0 = w.x - pi.x, dy0 = w.y - pi.y;
        const float r20 = fmaf(dx0, dx0, dy0 * dy0);
        const float dx1 = w.z - pi.x, dy1 = w.w - pi.y;
        const float r21 = fmaf(dx1, dx1, dy1 * dy1);
        if (r20 <= RCAND2) {              // candidate (incl. self; masked in B)
            const int j = 2 * t;
            atomicOr(&bmap[j >> 5], 1u << (j & 31));
            if (r20 <= RORC2) {           // inside_Ro
                const float2 uj = ori[j];
                oxs += uj.x; oys += uj.y;
                if (r20 <= RR2 && r20 > 0.f) {
                    // in_front fails <=> dot<=0 && cross>=0
                    const float dt_ = fmaf(dx0, uj.x, dy0 * uj.y);
                    const float cr_ = fmaf(dy0, uj.x, -dx0 * uj.y);
                    if (!((dt_ <= 0.f) && (cr_ >= 0.f))) {
                        nr += 1.f; sx += w.x; sy += w.y;
                    }
                }
            }
        }
        if (r21 <= RCAND2) {
            const int j = 2 * t + 1;
            atomicOr(&bmap[j >> 5], 1u << (j & 31));
            if (r21 <= RORC2) {
                const float2 uj = ori[j];
                oxs += uj.x; oys += uj.y;
                if (r21 <= RR2 && r21 > 0.f) {
                    const float dt_ = fmaf(dx1, uj.x, dy1 * uj.y);
                    const float cr_ = fmaf(dy1, uj.x, -dx1 * uj.y);
                    if (!((dt_ <= 0.f) && (cr_ >= 0.f))) {
                        nr += 1.f; sx += w.z; sy += w.w;
                    }
                }
            }
        }
    }
    {   // 64-lane shuffle reduction (whole wave belongs to one i)
        float vals[5] = {nr, sx, sy, oxs, oys};
        #pragma unroll
        for (int q = 0; q < 5; ++q)
            #pragma unroll
            for (int off = 32; off >= 1; off >>= 1)
                vals[q] += __shfl_down(vals[q], off);
        if (lane == 0) {
            res[0][il] = vals[0]; res[1][il] = vals[1]; res[2][il] = vals[2];
            res[3][il] = vals[3]; res[4][il] = vals[4];
        }
    }
    __syncthreads();                      // bmap + res final

    // ---- B. S-compaction from bmap (own-block nibble masked out) ----
    if (tid < NPART / 32) {
        unsigned bits = bmap[tid];
        if (tid == (int)(blockIdx.x >> 3))
            bits &= ~(0xFu << ((blockIdx.x & 7) * 4));
        while (bits) {
            const int b = __ffs(bits) - 1;
            bits &= bits - 1;
            const int slot = atomicAdd(&scnt, 1);
            if (slot < SMAX) Sidx[slot] = tid * 32 + b;
        }
    }
    __syncthreads();
    const int nS = (scnt < SMAX) ? scnt : SMAX;

    // ---- D1. translate S members (reference-exact expression) ----
    if (tid < nS) {
        const int p = Sidx[tid];
        const float2 pq = posL[p];
        const float2 uu = ori[p];
        const float2 tn = trans_noise[p];
        posS[tid] = make_float2(
            pq.x + (C_TRV * uu.x + ((tn.x * C_HALF) * C_SQ2T) * C_SQDT),
            pq.y + (C_TRV * uu.y + ((tn.y * C_HALF) * C_SQ2T) * C_SQDT));
    }

    // ---- C. mean of all positions (identical tree to the passing kernel) ----
    for (int s = NTHR / 2; s > 0; s >>= 1) {
        if (tid < s) { sred[tid] += sred[tid + s]; sred[NTHR + tid] += sred[NTHR + tid + s]; }
        __syncthreads();
    }
    const float cmx = sred[0]    * (1.f / NPART);
    const float cmy = sred[NTHR] * (1.f / NPART);

    // ---- C2. per-i epilogue (4 threads; sections 1..4) ----
    if (tid < IPB) {
        const int g2 = blockIdx.x * IPB + tid;
        const float2 p = posL[g2];
        const float2 u = ori[g2];
        const float nrv = res[0][tid], sxv = res[1][tid], syv = res[2][tid];
        const float osx = res[3][tid], osy = res[4][tid];

        const float inv = 1.f / fmaxf(nrv, 1.f);
        const float sg  = (nrv > 0.f) ? 1.f : 0.f;
        const float Sx = sxv * inv - p.x * sg;
        const float Sy = syv * inv - p.y * sg;
        const float dxv = -Sx, dyv = -Sy;        // d = -S

        const float Psx = cmx - p.x;
        const float Psy = cmy - p.y;

        float sd, cd;
        sincosf(Deltas[0], &sd, &cd);
        const float Lx = Psx * cd - Psy * sd;    // Ps * exp(+i*Delta)
        const float Ly = Psx * sd + Psy * cd;
        const float Rx = Psx * cd + Psy * sd;    // Ps * exp(-i*Delta)
        const float Ry = Psy * cd - Psx * sd;

        const float no  = fmaxf(sqrtf(osx * osx + osy * osy + 1e-30f), EPSF);
        const float nl  = fmaxf(sqrtf(Lx * Lx + Ly * Ly + 1e-30f), EPSF);
        const float nrr = fmaxf(sqrtf(Rx * Rx + Ry * Ry + 1e-30f), EPSF);
        const float csl = (Lx * osx + Ly * osy) / (nl * no);
        const float csr = (Rx * osx + Ry * osy) / (nrr * no);
        const bool left = (csl >= csr);
        const float bx = left ? Lx : Rx;
        const float by = left ? Ly : Ry;

        float cx, cy;
        if (dxv != 0.f || dyv != 0.f)    { cx = dxv; cy = dyv; }
        else if (bx != 0.f || by != 0.f) { cx = bx;  cy = by;  }
        else                             { cx = 1.f; cy = 0.f; }

        const float dt_ = cx * u.x + cy * u.y;
        const float cr_ = cy * u.x - cx * u.y;
        const float sin_t = cr_ / sqrtf(dt_ * dt_ + cr_ * cr_);

        const float ang = C_ROT * sin_t + (rot_noise[g2] * C_RN1) * C_SQDT;
        float sa, ca;
        sincosf(ang, &sa, &ca);
        out[1 * NPART + g2] = make_float2(u.x * ca - u.y * sa,
                                          u.x * sa + u.y * ca);
        out[2 * NPART + g2] = make_float2(osx, osy);
        out[3 * NPART + g2] = make_float2(Lx, Ly);
        out[4 * NPART + g2] = make_float2(Rx, Ry);
    }
    __syncthreads();                      // posS complete

    // ---- D2. three local JACOBI passes over S (nS <= 256 == NTHR) ----
    for (int pass = 0; pass < 3; ++pass) {
        float px = 0.f, py = 0.f, ax = 0.f, ay = 0.f;
        const bool mv = (tid < nS);
        if (mv) { px = posS[tid].x; py = posS[tid].y; }
        int b = 0;
        for (; b + 4 <= nS; b += 4) {
            const float4 w0 = posS4[(b >> 1)];
            const float4 w1 = posS4[(b >> 1) + 1];
            const float bxs[4] = {w0.x, w0.z, w1.x, w1.z};
            const float bys[4] = {w0.y, w0.w, w1.y, w1.w};
            #pragma unroll
            for (int s = 0; s < 4; ++s) {
                if (mv) {
                    const float dx = bxs[s] - px, dy = bys[s] - py;
                    const float r2 = fmaf(dx, dx, dy * dy);
                    if (r2 <= TWORC2 && r2 > 0.f) {
                        const float ab = sqrtf(r2);
                        const float sc = (C21RC - ab) * 0.5f / ab;
                        ax = fmaf(dx, sc, ax);
                        ay = fmaf(dy, sc, ay);
                    }
                }
            }
        }
        for (; b < nS; ++b) {
            const float2 pb = posS[b];
            if (mv) {
                const float dx = pb.x - px, dy = pb.y - py;
                const float r2 = fmaf(dx, dx, dy * dy);
                if (r2 <= TWORC2 && r2 > 0.f) {
                    const float ab = sqrtf(r2);
                    const float sc = (C21RC - ab) * 0.5f / ab;
                    ax = fmaf(dx, sc, ax);
                    ay = fmaf(dy, sc, ay);
                }
            }
        }
        __syncthreads();                  // all reads done (Jacobi)
        if (mv) posS[tid] = make_float2(px - ax, py - ay);
        __syncthreads();
    }
    // ---- section 0: own 4 i's are slots 0..3 of S ----
    if (tid < IPB)
        out[0 * NPART + blockIdx.x * IPB + tid] = posS[tid];
}

extern "C" void kernel_launch(void* const* d_in, const int* in_sizes, int n_in,
                              void* d_out, int out_size, void* d_ws, size_t ws_size,
                              hipStream_t stream) {
    const float2* pos = (const float2*)d_in[0];
    const float2* ori = (const float2*)d_in[1];
    const float*  del = (const float*)d_in[2];
    const float*  rn  = (const float*)d_in[3];
    const float2* tn  = (const float2*)d_in[4];
    float2* o2 = (float2*)d_out;          // [5][N] float2
    (void)d_ws; (void)ws_size;

    fused_all<<<dim3(NBLK), dim3(NTHR), 0, stream>>>(pos, ori, del, rn, tn, o2);
}